// Round 11
// baseline (443.178 us; speedup 1.0000x reference)
//
#include <hip/hip_runtime.h>
#include <hip/hip_bf16.h>
#include <hip/hip_cooperative_groups.h>

namespace cg = cooperative_groups;

#define NROW 8192   // B*A = 64*128
#define INC  128
#define OUTC 64
#define BG   16     // key-split factor

// Q is pre-scaled by log2(e)/sqrt(64) at projection time, so attention
// computes p = exp2(q'.k) with a single v_exp_f32 per score.
#define QSCALE 0.18033688011112042f

typedef __bf16 bf16x8 __attribute__((ext_vector_type(8)));
typedef __bf16 bf16x4 __attribute__((ext_vector_type(4)));
typedef short  s16x4  __attribute__((ext_vector_type(4)));
typedef short  s16x8  __attribute__((ext_vector_type(8)));
typedef float  f32x4  __attribute__((ext_vector_type(4)));

static __device__ __forceinline__ f32x4 mfma16(bf16x8 a, bf16x8 b, f32x4 c) {
    return __builtin_amdgcn_mfma_f32_16x16x32_bf16(a, b, c, 0, 0, 0);
}
// 16x16x16 bf16 (K=16). C/D of S^T IS the A-operand layout of P for PV.
static __device__ __forceinline__ f32x4 mfma1k(s16x4 a, s16x4 b, f32x4 c) {
    return __builtin_amdgcn_mfma_f32_16x16x16bf16_1k(a, b, c, 0, 0, 0);
}

static __device__ __forceinline__ bf16x8 cvt8(float4 lo, float4 hi) {
    bf16x8 r;
    r[0] = (__bf16)lo.x; r[1] = (__bf16)lo.y; r[2] = (__bf16)lo.z; r[3] = (__bf16)lo.w;
    r[4] = (__bf16)hi.x; r[5] = (__bf16)hi.y; r[6] = (__bf16)hi.z; r[7] = (__bf16)hi.w;
    return r;
}
static __device__ __forceinline__ s16x4 vlo(s16x8 x) {
    return __builtin_shufflevector(x, x, 0, 1, 2, 3);
}
static __device__ __forceinline__ s16x4 vhi(s16x8 x) {
    return __builtin_shufflevector(x, x, 4, 5, 6, 7);
}

// ---------------------------------------------------------------------------
// shared phase bodies (r9 verbatim)

#define STAGE_W(BUF, KR, VR) do {                                            \
        *(float4*)((BUF) + stb) = KR;                                        \
        *(float4*)((BUF) + 4096 + stb) = VR; } while (0)
#define STAGE_L(KR, VR) do {                                                 \
        KR = *(const float4*)gk; VR = *(const float4*)gv;                    \
        gk += 4096; gv += 4096; } while (0)

#define COMPUTE(BUF) do {                                                    \
    const char* kbp = (BUF);                                                 \
    const char* vbp = (BUF) + 4096;                                          \
    bf16x8 k00 = *(const bf16x8*)(kbp + lb);                                 \
    bf16x8 k01 = *(const bf16x8*)(kbp + lb + 1024);                          \
    bf16x8 k10 = *(const bf16x8*)(kbp + lb + 2048);                          \
    bf16x8 k11 = *(const bf16x8*)(kbp + lb + 3072);                          \
    s16x8 W0 = *(const s16x8*)(vbp + lb);                                    \
    s16x8 W1 = *(const s16x8*)(vbp + lb + 1024);                             \
    s16x8 W2 = *(const s16x8*)(vbp + lb + 2048);                             \
    s16x8 W3 = *(const s16x8*)(vbp + lb + 3072);                             \
    const f32x4 zero = (f32x4){0.f, 0.f, 0.f, 0.f};                          \
    _Pragma("unroll")                                                        \
    for (int u = 0; u < 4; ++u) {                                            \
        f32x4 s0 = mfma16(k00, qf32[u][0], zero);                            \
        s0       = mfma16(k01, qf32[u][1], s0);                              \
        f32x4 s1 = mfma16(k10, qf32[u][0], zero);                            \
        s1       = mfma16(k11, qf32[u][1], s1);                              \
        union { bf16x4 v; s16x4 s; } pf0, pf1;                               \
        _Pragma("unroll")                                                    \
        for (int r = 0; r < 4; ++r) {                                        \
            float p0 = __builtin_amdgcn_exp2f(s0[r]);                        \
            float p1 = __builtin_amdgcn_exp2f(s1[r]);                        \
            lp[u] += p0 + p1;                                                \
            pf0.v[r] = (__bf16)p0;                                           \
            pf1.v[r] = (__bf16)p1;                                           \
        }                                                                    \
        of[u][0] = mfma1k(pf0.s, vlo(W0), of[u][0]);                         \
        of[u][0] = mfma1k(pf1.s, vlo(W2), of[u][0]);                         \
        of[u][1] = mfma1k(pf0.s, vhi(W0), of[u][1]);                         \
        of[u][1] = mfma1k(pf1.s, vhi(W2), of[u][1]);                         \
        of[u][2] = mfma1k(pf0.s, vlo(W1), of[u][2]);                         \
        of[u][2] = mfma1k(pf1.s, vlo(W3), of[u][2]);                         \
        of[u][3] = mfma1k(pf0.s, vhi(W1), of[u][3]);                         \
        of[u][3] = mfma1k(pf1.s, vhi(W3), of[u][3]);                         \
    } } while (0)

// proj body, parameterized on LDS pointers. Writes qbf (frag-tiled,
// pre-scaled), kbf/vbf (fragment-linear), vnb (row-major normalized).
#define PROJ_BODY(BID)                                                       \
    do {                                                                     \
        const int b   = (BID) >> 2;                                          \
        const int a0  = ((BID) & 3) * 32;                                    \
        const int r0  = b * 128 + a0;                                        \
        const float* fb = feat + (size_t)b * INC * 128;                      \
        for (int i = tid; i < 32 * 128; i += 256) {                          \
            int c = i >> 5, a = i & 31;                                      \
            slab[a * 132 + c] = fb[c * 128 + a0 + a];                        \
        }                                                                    \
        __syncthreads();                                                     \
        f32x4 acc[3][2];                                                     \
        _Pragma("unroll")                                                    \
        for (int t = 0; t < 3; ++t)                                          \
            _Pragma("unroll")                                                \
            for (int u = 0; u < 2; ++u)                                      \
                acc[t][u] = (f32x4){0.f, 0.f, 0.f, 0.f};                     \
        _Pragma("unroll")                                                    \
        for (int kc = 0; kc < 4; ++kc) {                                     \
            const int k0 = kc * 32 + quad * 8;                               \
            bf16x8 afr[2];                                                   \
            _Pragma("unroll")                                                \
            for (int u = 0; u < 2; ++u) {                                    \
                const float* ar = slab + (u * 16 + l16) * 132 + k0;          \
                afr[u] = cvt8(*(const float4*)ar, *(const float4*)(ar + 4)); \
            }                                                                \
            _Pragma("unroll")                                                \
            for (int t = 0; t < 3; ++t) {                                    \
                const int tile = w * 3 + t;                                  \
                const int mat  = tile >> 2;                                  \
                const float* W = (mat == 0) ? Wq : (mat == 1) ? Wk : Wv;     \
                const float* wr = W + ((tile & 3) * 16 + l16) * INC + k0;    \
                bf16x8 bfr = cvt8(*(const float4*)wr, *(const float4*)(wr + 4)); \
                _Pragma("unroll")                                            \
                for (int u = 0; u < 2; ++u)                                  \
                    acc[t][u] = mfma16(afr[u], bfr, acc[t][u]);              \
            }                                                                \
        }                                                                    \
        _Pragma("unroll")                                                    \
        for (int t = 0; t < 3; ++t) {                                        \
            const int tile = w * 3 + t;                                      \
            const int mat  = tile >> 2;                                      \
            const int nt   = tile & 3;                                       \
            const float* bias = (mat == 0) ? bq : (mat == 1) ? bk : bv;      \
            const float bl = bias[nt * 16 + l16];                            \
            if (mat == 0) {                                                  \
                _Pragma("unroll")                                            \
                for (int u = 0; u < 2; ++u) {                                \
                    const int base = ((((r0 >> 4) + u) * 4 + nt) << 8) + l16;\
                    _Pragma("unroll")                                        \
                    for (int r = 0; r < 4; ++r)                              \
                        qbf[base + (quad * 4 + r) * 16] =                    \
                            __float2bfloat16((acc[t][u][r] + bl) * QSCALE);  \
                }                                                            \
            } else if (mat == 1) {                                           \
                const int kq = (r0 >> 5) * 2048 + (nt >> 1) * 512 +          \
                    ((nt & 1) * 2 + (l16 >> 3)) * 128 + quad * 32 + (l16 & 7);\
                _Pragma("unroll")                                            \
                for (int u = 0; u < 2; ++u)                                  \
                    _Pragma("unroll")                                        \
                    for (int r = 0; r < 4; ++r)                              \
                        kbf[kq + u * 1024 + r * 8] =                         \
                            __float2bfloat16(acc[t][u][r] + bl);             \
            } else {                                                         \
                _Pragma("unroll")                                            \
                for (int u = 0; u < 2; ++u)                                  \
                    _Pragma("unroll")                                        \
                    for (int r = 0; r < 4; ++r)                              \
                        vbuf[(u * 16 + quad * 4 + r) * 66 + nt * 16 + l16] = \
                            acc[t][u][r] + bl;                               \
            }                                                                \
        }                                                                    \
        __syncthreads();                                                     \
        const int rl = tid >> 3;                                             \
        const int jj = tid & 7;                                              \
        float ss = 0.f;                                                      \
        _Pragma("unroll")                                                    \
        for (int i = 0; i < 8; ++i) {                                        \
            float x = vbuf[rl * 66 + jj * 8 + i];                            \
            ss += x * x;                                                     \
        }                                                                    \
        ss += __shfl_xor(ss, 1, 64);                                         \
        ss += __shfl_xor(ss, 2, 64);                                         \
        ss += __shfl_xor(ss, 4, 64);                                         \
        if (jj == 0) invb[rl] = rsqrtf(fmaxf(ss, 1e-24f));                   \
        __syncthreads();                                                     \
        float inv = invb[rl];                                                \
        bf16x8 vpk;                                                          \
        _Pragma("unroll")                                                    \
        for (int i = 0; i < 8; ++i)                                          \
            vpk[i] = (__bf16)(vbuf[rl * 66 + jj * 8 + i] * inv);             \
        *(bf16x8*)(vnb + (size_t)(r0 + rl) * 64 + jj * 8) = vpk;             \
        const int tl = tid & 15;                                             \
        const int n  = (tid >> 4) & 3;                                       \
        const int s_ = tid >> 6;                                             \
        bf16x8 pack;                                                         \
        _Pragma("unroll")                                                    \
        for (int j = 0; j < 8; ++j) {                                        \
            int key = s_ * 8 + j;                                            \
            pack[j] = (__bf16)(vbuf[key * 66 + n * 16 + tl] * invb[key]);    \
        }                                                                    \
        const int e1 = (r0 >> 5) * 2048 + (s_ >> 1) * 1024 + (n >> 1) * 512 +\
                       (s_ & 1) * 256 + tl * 8 + (n & 1) * 4;                \
        bf16x4 plo = __builtin_shufflevector(pack, pack, 0, 1, 2, 3);        \
        bf16x4 phi = __builtin_shufflevector(pack, pack, 4, 5, 6, 7);        \
        *(bf16x4*)(vbf + e1)       = plo;                                    \
        *(bf16x4*)(vbf + e1 + 128) = phi;                                    \
    } while (0)

#define ATTN_BODY(BID, BUFA, BUFB)                                           \
    do {                                                                     \
        const int qb   = (BID) >> 4;                                         \
        const int bg   = (BID) & 15;                                         \
        const int r0   = qb * 256 + w * 64;                                  \
        const int fo32 = l16 * 16 + (quad & 1) * 8;                          \
        const int qh   = quad >> 1;                                          \
        const int lb   = lane * 16;                                          \
        const int stb  = tid * 16;                                           \
        bf16x8 qf32[4][2];                                                   \
        _Pragma("unroll")                                                    \
        for (int u = 0; u < 4; ++u)                                          \
            _Pragma("unroll")                                                \
            for (int p = 0; p < 2; ++p)                                      \
                qf32[u][p] = *(const bf16x8*)(qbf +                          \
                    ((((r0 >> 4) + u) * 4 + p * 2 + qh) << 8) + fo32);       \
        f32x4 of[4][4];                                                      \
        float lp[4] = {0.f, 0.f, 0.f, 0.f};                                  \
        _Pragma("unroll")                                                    \
        for (int u = 0; u < 4; ++u)                                          \
            _Pragma("unroll")                                                \
            for (int n = 0; n < 4; ++n)                                      \
                of[u][n] = (f32x4){0.f, 0.f, 0.f, 0.f};                      \
        const char* gk = (const char*)kbf + (size_t)(bg * 16) * 4096 + stb;  \
        const char* gv = (const char*)vbf + (size_t)(bg * 16) * 4096 + stb;  \
        float4 ka, va, kb_, vb_;                                             \
        STAGE_L(ka, va);                                                     \
        STAGE_W(BUFA, ka, va);                                               \
        STAGE_L(kb_, vb_);                                                   \
        __syncthreads();                                                     \
        _Pragma("unroll 1")                                                  \
        for (int body = 0; body < 7; ++body) {                               \
            STAGE_W(BUFB, kb_, vb_);                                         \
            STAGE_L(ka, va);                                                 \
            COMPUTE(BUFA);                                                   \
            __syncthreads();                                                 \
            STAGE_W(BUFA, ka, va);                                           \
            STAGE_L(kb_, vb_);                                               \
            COMPUTE(BUFB);                                                   \
            __syncthreads();                                                 \
        }                                                                    \
        STAGE_W(BUFB, kb_, vb_);                                             \
        COMPUTE(BUFA);                                                       \
        __syncthreads();                                                     \
        COMPUTE(BUFB);                                                       \
        _Pragma("unroll")                                                    \
        for (int u = 0; u < 4; ++u) {                                        \
            float v = lp[u];                                                 \
            v += __shfl_xor(v, 16, 64);                                      \
            v += __shfl_xor(v, 32, 64);                                      \
            lp[u] = v;                                                       \
        }                                                                    \
        const int task = (qb * 4 + w) * 16 + bg;                             \
        float* Ob = Opart + (size_t)task * 4096;                             \
        _Pragma("unroll")                                                    \
        for (int u = 0; u < 4; ++u)                                          \
            _Pragma("unroll")                                                \
            for (int n = 0; n < 4; ++n)                                      \
                _Pragma("unroll")                                            \
                for (int r = 0; r < 4; ++r)                                  \
                    Ob[(u * 16 + quad * 4 + r) * 64 + n * 16 + l16] =        \
                        of[u][n][r];                                         \
        if (quad == 0) {                                                     \
            _Pragma("unroll")                                                \
            for (int u = 0; u < 4; ++u)                                      \
                lpart[task * 64 + u * 16 + l16] = lp[u];                     \
        }                                                                    \
    } while (0)

// ---------------------------------------------------------------------------
// ROUND 11: cooperative mega-kernel, LDS overlaid into ONE 25.4 KB pool
// (r10's 41.9 KB/block made the cooperative occupancy check fail: 1
// block/CU under the 64 KB budget -> 256 max < 512 requested -> launch
// error silently swallowed -> output stayed zero, absmax 0.1226 = max|ref|).
// 25.4 KB x 2 = 50.9 KB < 64 KB -> 2 blocks/CU validates. Phase bodies are
// r9 verbatim. Launch errors now CHECKED, with a fallback to the r9
// 4-kernel path so a validation failure costs parity, not correctness.
__global__ __launch_bounds__(256, 2) void mega_kernel(
    const float* __restrict__ feat,
    const float* __restrict__ Wq, const float* __restrict__ bq,
    const float* __restrict__ Wk, const float* __restrict__ bk,
    const float* __restrict__ Wv, const float* __restrict__ bv,
    __hip_bfloat16* __restrict__ qbf, __hip_bfloat16* __restrict__ kbf,
    __hip_bfloat16* __restrict__ vbf, __hip_bfloat16* __restrict__ vnb,
    float* __restrict__ Opart, float* __restrict__ lpart,
    __hip_bfloat16* __restrict__ qnb, float* __restrict__ out)
{
    cg::grid_group gg = cg::this_grid();

    // one overlaid pool: P0 needs slab(16896)+vbuf(8448)+invb(128)=25472 B;
    // P1 needs 2x8192=16384 B. Phases separated by grid syncs.
    __shared__ __align__(16) char pool[25472];

    const int bid = blockIdx.x;
    const int tid = threadIdx.x;
    const int w    = tid >> 6;
    const int lane = tid & 63;
    const int l16  = lane & 15;
    const int quad = lane >> 4;

    // ======================= P0: projection (blocks 0..255) ================
    if (bid < 256) {
        float* slab = (float*)pool;
        float* vbuf = (float*)(pool + 16896);
        float* invb = (float*)(pool + 25344);
        PROJ_BODY(bid);
    }
    __threadfence();
    gg.sync();

    // ======================= P1: attention (all 512 blocks) ================
    {
        char* bufA = pool;
        char* bufB = pool + 8192;
        ATTN_BODY(bid, bufA, bufB);
    }
    __threadfence();
    gg.sync();

    // ======================= P2: combine (512 blocks x 4 strides) ==========
    {
        if (bid == 0) {
            #pragma unroll
            for (int z = 0; z < 4; ++z)
                ((float4*)out)[tid * 4 + z] = (float4){0.f, 0.f, 0.f, 0.f};
        }
        #pragma unroll 1
        for (int it = 0; it < 4; ++it) {
            const int r    = (it * 512 + bid) * 4 + (tid >> 6);
            const int c    = tid & 63;
            const int tile = r >> 6, row = r & 63;
            float acc = 0.f, lsum = 0.f;
            #pragma unroll
            for (int g = 0; g < 16; ++g) {
                int task = tile * 16 + g;
                acc  += Opart[(size_t)task * 4096 + row * 64 + c];
                lsum += lpart[task * 64 + row];
            }
            float q = acc / lsum;
            float ss = q * q;
            ss += __shfl_xor(ss, 1, 64);
            ss += __shfl_xor(ss, 2, 64);
            ss += __shfl_xor(ss, 4, 64);
            ss += __shfl_xor(ss, 8, 64);
            ss += __shfl_xor(ss, 16, 64);
            ss += __shfl_xor(ss, 32, 64);
            qnb[(size_t)r * 64 + c] = __float2bfloat16(q * rsqrtf(fmaxf(ss, 1e-24f)));
        }
    }
    __threadfence();
    gg.sync();

    // ======================= P3: sim GEMM (blocks 0..255) ==================
    if (bid < 256) {
        const int k0 = bid * 32 + quad * 8;
        f32x4 acc[4];
        #pragma unroll
        for (int ni = 0; ni < 4; ++ni)
            acc[ni] = (f32x4){0.f, 0.f, 0.f, 0.f};

        bf16x8 af = *(const bf16x8*)(vnb + (size_t)(w * 16 + l16) * 8192 + k0);
        bf16x8 bfv[4];
        #pragma unroll
        for (int ni = 0; ni < 4; ++ni)
            bfv[ni] = *(const bf16x8*)(qnb + (size_t)(ni * 16 + l16) * 8192 + k0);
        #pragma unroll
        for (int ni = 0; ni < 4; ++ni)
            acc[ni] = mfma16(af, bfv[ni], acc[ni]);

        #pragma unroll
        for (int ni = 0; ni < 4; ++ni)
            #pragma unroll
            for (int r = 0; r < 4; ++r)
                atomicAdd(&out[(w * 16 + quad * 4 + r) * 64 + ni * 16 + l16],
                          acc[ni][r] * (1.f / 128.f));
    }
}

// ---------------------------------------------------------------------------
// Fallback path: r9 4-kernel pipeline (known-good, 121.6 us).
__global__ __launch_bounds__(256) void proj_kernel(
    const float* __restrict__ feat,
    const float* __restrict__ Wq, const float* __restrict__ bq,
    const float* __restrict__ Wk, const float* __restrict__ bk,
    const float* __restrict__ Wv, const float* __restrict__ bv,
    __hip_bfloat16* __restrict__ qbf, __hip_bfloat16* __restrict__ kbf,
    __hip_bfloat16* __restrict__ vbf, __hip_bfloat16* __restrict__ vnb)
{
    __shared__ float slab[32 * 132];
    __shared__ float vbuf[32 * 66];
    __shared__ float invb[32];
    const int tid = threadIdx.x;
    const int w    = tid >> 6;
    const int lane = tid & 63;
    const int l16  = lane & 15;
    const int quad = lane >> 4;
    PROJ_BODY(blockIdx.x);
}

__global__ __launch_bounds__(256, 2) void attn_kernel(
    const __hip_bfloat16* __restrict__ qbf,
    const __hip_bfloat16* __restrict__ kbf,
    const __hip_bfloat16* __restrict__ vbf,
    float* __restrict__ Opart, float* __restrict__ lpart)
{
    __shared__ __align__(16) char pool[16384];
    const int tid = threadIdx.x;
    const int w    = tid >> 6;
    const int lane = tid & 63;
    const int l16  = lane & 15;
    const int quad = lane >> 4;
    char* bufA = pool;
    char* bufB = pool + 8192;
    ATTN_BODY(blockIdx.x, bufA, bufB);
}

__global__ __launch_bounds__(256) void combine_kernel(
    const float* __restrict__ Opart, const float* __restrict__ lpart,
    __hip_bfloat16* __restrict__ qnb, float* __restrict__ outz)
{
    if (blockIdx.x == 0) {
        #pragma unroll
        for (int z = 0; z < 4; ++z)
            ((float4*)outz)[threadIdx.x * 4 + z] = (float4){0.f, 0.f, 0.f, 0.f};
    }
    const int r    = blockIdx.x * 4 + (threadIdx.x >> 6);
    const int c    = threadIdx.x & 63;
    const int tile = r >> 6, row = r & 63;
    float acc = 0.f, lsum = 0.f;
    #pragma unroll
    for (int g = 0; g < 16; ++g) {
        int task = tile * 16 + g;
        acc  += Opart[(size_t)task * 4096 + row * 64 + c];
        lsum += lpart[task * 64 + row];
    }
    float q = acc / lsum;
    float ss = q * q;
    ss += __shfl_xor(ss, 1, 64);
    ss += __shfl_xor(ss, 2, 64);
    ss += __shfl_xor(ss, 4, 64);
    ss += __shfl_xor(ss, 8, 64);
    ss += __shfl_xor(ss, 16, 64);
    ss += __shfl_xor(ss, 32, 64);
    qnb[(size_t)r * 64 + c] = __float2bfloat16(q * rsqrtf(fmaxf(ss, 1e-24f)));
}

__global__ __launch_bounds__(256) void sim_kernel(
    const __hip_bfloat16* __restrict__ vnb,
    const __hip_bfloat16* __restrict__ qnb,
    float* __restrict__ out)
{
    const int w    = threadIdx.x >> 6;
    const int lane = threadIdx.x & 63;
    const int l16  = lane & 15;
    const int quad = lane >> 4;
    const int k0   = blockIdx.x * 128 + w * 32 + quad * 8;

    f32x4 acc[4][4];
    #pragma unroll
    for (int mi = 0; mi < 4; ++mi)
        #pragma unroll
        for (int ni = 0; ni < 4; ++ni)
            acc[mi][ni] = (f32x4){0.f, 0.f, 0.f, 0.f};

    bf16x8 af[4], bfv[4];
    #pragma unroll
    for (int mi = 0; mi < 4; ++mi)
        af[mi] = *(const bf16x8*)(vnb + (size_t)(mi * 16 + l16) * 8192 + k0);
    #pragma unroll
    for (int ni = 0; ni < 4; ++ni)
        bfv[ni] = *(const bf16x8*)(qnb + (size_t)(ni * 16 + l16) * 8192 + k0);
    #pragma unroll
    for (int mi = 0; mi < 4; ++mi)
        #pragma unroll
        for (int ni = 0; ni < 4; ++ni)
            acc[mi][ni] = mfma16(af[mi], bfv[ni], acc[mi][ni]);

    #pragma unroll
    for (int mi = 0; mi < 4; ++mi)
        #pragma unroll
        for (int ni = 0; ni < 4; ++ni)
            #pragma unroll
            for (int r = 0; r < 4; ++r)
                atomicAdd(&out[(mi * 16 + quad * 4 + r) * 64 + ni * 16 + l16],
                          acc[mi][ni][r] * (1.f / 128.f));
}

// ---------------------------------------------------------------------------
extern "C" void kernel_launch(void* const* d_in, const int* in_sizes, int n_in,
                              void* d_out, int out_size, void* d_ws, size_t ws_size,
                              hipStream_t stream)
{
    const float* feat = (const float*)d_in[0];
    const float* Wq   = (const float*)d_in[1];
    const float* bq   = (const float*)d_in[2];
    const float* Wk   = (const float*)d_in[3];
    const float* bk   = (const float*)d_in[4];
    const float* Wv   = (const float*)d_in[5];
    const float* bv   = (const float*)d_in[6];
    float* out = (float*)d_out;

    const size_t MB = 1u << 20;
    char* ws = (char*)d_ws;
    __hip_bfloat16* qbf = (__hip_bfloat16*)(ws);              // 1 MB (frag-tiled, pre-scaled)
    __hip_bfloat16* kbf = (__hip_bfloat16*)(ws + 1 * MB);     // 1 MB (fragment-linear)
    __hip_bfloat16* vbf = (__hip_bfloat16*)(ws + 2 * MB);     // 1 MB (fragment-linear)
    __hip_bfloat16* vnb = (__hip_bfloat16*)(ws + 3 * MB);     // 1 MB (row-major)
    float* Opart = (float*)(ws + 4 * MB);                     // 32 MB (2048 x 16 KB)
    float* lpart = (float*)(ws + 36 * MB);                    // 512 KB
    __hip_bfloat16* qnb = (__hip_bfloat16*)(ws + 37 * MB);    // 1 MB

    void* args[] = {
        (void*)&feat, (void*)&Wq, (void*)&bq, (void*)&Wk, (void*)&bk,
        (void*)&Wv, (void*)&bv, (void*)&qbf, (void*)&kbf, (void*)&vbf,
        (void*)&vnb, (void*)&Opart, (void*)&lpart, (void*)&qnb, (void*)&out
    };
    hipError_t err = hipLaunchCooperativeKernel((const void*)mega_kernel,
                                                dim3(512), dim3(256), args, 0, stream);
    if (err != hipSuccess) {
        // fallback: known-good r9 4-kernel pipeline
        proj_kernel<<<256, 256, 0, stream>>>(feat, Wq, bq, Wk, bk, Wv, bv,
                                             qbf, kbf, vbf, vnb);
        attn_kernel<<<512, 256, 0, stream>>>(qbf, kbf, vbf, Opart, lpart);
        combine_kernel<<<2048, 256, 0, stream>>>(Opart, lpart, qnb, out);
        sim_kernel<<<64, 256, 0, stream>>>(vnb, qnb, out);
    }
}

// Round 12
// 113.884 us; speedup vs baseline: 3.8915x; 3.8915x over previous
//
#include <hip/hip_runtime.h>
#include <hip/hip_bf16.h>

#define NROW 8192   // B*A = 64*128
#define INC  128
#define OUTC 64
#define BG   16     // key-split factor

// Q is pre-scaled by log2(e)/sqrt(64) at projection time, so attention
// computes p = exp2(q'.k) with a single v_exp_f32 per score.
#define QSCALE 0.18033688011112042f

typedef __bf16 bf16x8 __attribute__((ext_vector_type(8)));
typedef __bf16 bf16x4 __attribute__((ext_vector_type(4)));
typedef short  s16x4  __attribute__((ext_vector_type(4)));
typedef short  s16x8  __attribute__((ext_vector_type(8)));
typedef float  f32x4  __attribute__((ext_vector_type(4)));

static __device__ __forceinline__ f32x4 mfma16(bf16x8 a, bf16x8 b, f32x4 c) {
    return __builtin_amdgcn_mfma_f32_16x16x32_bf16(a, b, c, 0, 0, 0);
}
// 16x16x16 bf16 (K=16). C/D of S^T IS the A-operand layout of P for PV.
static __device__ __forceinline__ f32x4 mfma1k(s16x4 a, s16x4 b, f32x4 c) {
    return __builtin_amdgcn_mfma_f32_16x16x16bf16_1k(a, b, c, 0, 0, 0);
}

static __device__ __forceinline__ bf16x8 cvt8(float4 lo, float4 hi) {
    bf16x8 r;
    r[0] = (__bf16)lo.x; r[1] = (__bf16)lo.y; r[2] = (__bf16)lo.z; r[3] = (__bf16)lo.w;
    r[4] = (__bf16)hi.x; r[5] = (__bf16)hi.y; r[6] = (__bf16)hi.z; r[7] = (__bf16)hi.w;
    return r;
}
static __device__ __forceinline__ s16x4 vlo(s16x8 x) {
    return __builtin_shufflevector(x, x, 0, 1, 2, 3);
}
static __device__ __forceinline__ s16x4 vhi(s16x8 x) {
    return __builtin_shufflevector(x, x, 4, 5, 6, 7);
}

// ---------------------------------------------------------------------------
// Kernel 1: projection via MFMA. grid = 256 = b(64) x aq(4), 1 block/CU.
// Slab staged once; 12 n-tiles (3 mats x 4) spread 3-per-wave. qbf is
// frag-tiled + pre-scaled; kbf/vbf fragment-linear (attn LDS staging is a
// linear tid*16 copy, ds_read_b128 conflict-free); vnb row-major normalized.
__global__ __launch_bounds__(256) void proj_kernel(
    const float* __restrict__ feat,
    const float* __restrict__ Wq, const float* __restrict__ bq,
    const float* __restrict__ Wk, const float* __restrict__ bk,
    const float* __restrict__ Wv, const float* __restrict__ bv,
    __hip_bfloat16* __restrict__ qbf, __hip_bfloat16* __restrict__ kbf,
    __hip_bfloat16* __restrict__ vbf, __hip_bfloat16* __restrict__ vnb)
{
    __shared__ float slab[32 * 132];
    __shared__ float vbuf[32 * 66];
    __shared__ float invb[32];

    const int tid = threadIdx.x;
    const int w    = tid >> 6;
    const int lane = tid & 63;
    const int l16  = lane & 15;
    const int quad = lane >> 4;

    const int b   = blockIdx.x >> 2;
    const int a0  = (blockIdx.x & 3) * 32;
    const int r0  = b * 128 + a0;
    const float* fb = feat + (size_t)b * INC * 128;

    for (int i = tid; i < 32 * 128; i += 256) {
        int c = i >> 5, a = i & 31;
        slab[a * 132 + c] = fb[c * 128 + a0 + a];
    }
    __syncthreads();

    f32x4 acc[3][2];
    #pragma unroll
    for (int t = 0; t < 3; ++t)
        #pragma unroll
        for (int u = 0; u < 2; ++u)
            acc[t][u] = (f32x4){0.f, 0.f, 0.f, 0.f};

    #pragma unroll
    for (int kc = 0; kc < 4; ++kc) {
        const int k0 = kc * 32 + quad * 8;
        bf16x8 afr[2];
        #pragma unroll
        for (int u = 0; u < 2; ++u) {
            const float* ar = slab + (u * 16 + l16) * 132 + k0;
            afr[u] = cvt8(*(const float4*)ar, *(const float4*)(ar + 4));
        }
        #pragma unroll
        for (int t = 0; t < 3; ++t) {
            const int tile = w * 3 + t;
            const int mat  = tile >> 2;
            const float* W = (mat == 0) ? Wq : (mat == 1) ? Wk : Wv;
            const float* wr = W + ((tile & 3) * 16 + l16) * INC + k0;
            bf16x8 bfr = cvt8(*(const float4*)wr, *(const float4*)(wr + 4));
            #pragma unroll
            for (int u = 0; u < 2; ++u)
                acc[t][u] = mfma16(afr[u], bfr, acc[t][u]);
        }
    }

    #pragma unroll
    for (int t = 0; t < 3; ++t) {
        const int tile = w * 3 + t;
        const int mat  = tile >> 2;
        const int nt   = tile & 3;
        const float* bias = (mat == 0) ? bq : (mat == 1) ? bk : bv;
        const float bl = bias[nt * 16 + l16];
        if (mat == 0) {
            #pragma unroll
            for (int u = 0; u < 2; ++u) {
                const int base = ((((r0 >> 4) + u) * 4 + nt) << 8) + l16;
                #pragma unroll
                for (int r = 0; r < 4; ++r)
                    qbf[base + (quad * 4 + r) * 16] =
                        __float2bfloat16((acc[t][u][r] + bl) * QSCALE);
            }
        } else if (mat == 1) {
            const int kq = (r0 >> 5) * 2048 + (nt >> 1) * 512 +
                           ((nt & 1) * 2 + (l16 >> 3)) * 128 + quad * 32 + (l16 & 7);
            #pragma unroll
            for (int u = 0; u < 2; ++u)
                #pragma unroll
                for (int r = 0; r < 4; ++r)
                    kbf[kq + u * 1024 + r * 8] = __float2bfloat16(acc[t][u][r] + bl);
        } else {
            #pragma unroll
            for (int u = 0; u < 2; ++u)
                #pragma unroll
                for (int r = 0; r < 4; ++r)
                    vbuf[(u * 16 + quad * 4 + r) * 66 + nt * 16 + l16] = acc[t][u][r] + bl;
        }
    }
    __syncthreads();

    // ---- V normalize phase (block-wide) ----
    const int rl = tid >> 3;
    const int jj = tid & 7;
    float ss = 0.f;
    #pragma unroll
    for (int i = 0; i < 8; ++i) {
        float x = vbuf[rl * 66 + jj * 8 + i];
        ss += x * x;
    }
    ss += __shfl_xor(ss, 1, 64);
    ss += __shfl_xor(ss, 2, 64);
    ss += __shfl_xor(ss, 4, 64);
    if (jj == 0) invb[rl] = rsqrtf(fmaxf(ss, 1e-24f));
    __syncthreads();
    float inv = invb[rl];
    bf16x8 vpk;
    #pragma unroll
    for (int i = 0; i < 8; ++i)
        vpk[i] = (__bf16)(vbuf[rl * 66 + jj * 8 + i] * inv);
    *(bf16x8*)(vnb + (size_t)(r0 + rl) * 64 + jj * 8) = vpk;

    const int tl = tid & 15;
    const int n  = (tid >> 4) & 3;
    const int s_ = tid >> 6;
    bf16x8 pack;
    #pragma unroll
    for (int j = 0; j < 8; ++j) {
        int key = s_ * 8 + j;
        pack[j] = (__bf16)(vbuf[key * 66 + n * 16 + tl] * invb[key]);
    }
    const int e1 = (r0 >> 5) * 2048 + (s_ >> 1) * 1024 + (n >> 1) * 512 +
                   (s_ & 1) * 256 + tl * 8 + (n & 1) * 4;
    bf16x4 plo = __builtin_shufflevector(pack, pack, 0, 1, 2, 3);
    bf16x4 phi = __builtin_shufflevector(pack, pack, 4, 5, 6, 7);
    *(bf16x4*)(vbf + e1)       = plo;
    *(bf16x4*)(vbf + e1 + 128) = phi;
}

// ---------------------------------------------------------------------------
// Kernel 2: attention. grid = 512 = qb(32) x bg(16); block = 256 q-rows x
// 512 keys; 2 blocks/CU (r5 optimum tiling). K/V LDS-staged, double
// buffered. Opart now in ROW-MAJOR-PARTIALS layout [row][g][64] so the
// finish kernel streams each row's 16 partials as one contiguous 4 KB.
// Block 0 zeroes the 16 KB output (before finish's atomics).
#define STAGE_W(BUF, KR, VR) do {                                            \
        *(float4*)((BUF) + stb) = KR;                                        \
        *(float4*)((BUF) + 4096 + stb) = VR; } while (0)
#define STAGE_L(KR, VR) do {                                                 \
        KR = *(const float4*)gk; VR = *(const float4*)gv;                    \
        gk += 4096; gv += 4096; } while (0)

#define COMPUTE(BUF) do {                                                    \
    const char* kbp = (BUF);                                                 \
    const char* vbp = (BUF) + 4096;                                          \
    bf16x8 k00 = *(const bf16x8*)(kbp + lb);                                 \
    bf16x8 k01 = *(const bf16x8*)(kbp + lb + 1024);                          \
    bf16x8 k10 = *(const bf16x8*)(kbp + lb + 2048);                          \
    bf16x8 k11 = *(const bf16x8*)(kbp + lb + 3072);                          \
    s16x8 W0 = *(const s16x8*)(vbp + lb);                                    \
    s16x8 W1 = *(const s16x8*)(vbp + lb + 1024);                             \
    s16x8 W2 = *(const s16x8*)(vbp + lb + 2048);                             \
    s16x8 W3 = *(const s16x8*)(vbp + lb + 3072);                             \
    const f32x4 zero = (f32x4){0.f, 0.f, 0.f, 0.f};                          \
    _Pragma("unroll")                                                        \
    for (int u = 0; u < 4; ++u) {                                            \
        f32x4 s0 = mfma16(k00, qf32[u][0], zero);                            \
        s0       = mfma16(k01, qf32[u][1], s0);                              \
        f32x4 s1 = mfma16(k10, qf32[u][0], zero);                            \
        s1       = mfma16(k11, qf32[u][1], s1);                              \
        union { bf16x4 v; s16x4 s; } pf0, pf1;                               \
        _Pragma("unroll")                                                    \
        for (int r = 0; r < 4; ++r) {                                        \
            float p0 = __builtin_amdgcn_exp2f(s0[r]);                        \
            float p1 = __builtin_amdgcn_exp2f(s1[r]);                        \
            lp[u] += p0 + p1;                                                \
            pf0.v[r] = (__bf16)p0;                                           \
            pf1.v[r] = (__bf16)p1;                                           \
        }                                                                    \
        of[u][0] = mfma1k(pf0.s, vlo(W0), of[u][0]);                         \
        of[u][0] = mfma1k(pf1.s, vlo(W2), of[u][0]);                         \
        of[u][1] = mfma1k(pf0.s, vhi(W0), of[u][1]);                         \
        of[u][1] = mfma1k(pf1.s, vhi(W2), of[u][1]);                         \
        of[u][2] = mfma1k(pf0.s, vlo(W1), of[u][2]);                         \
        of[u][2] = mfma1k(pf1.s, vlo(W3), of[u][2]);                         \
        of[u][3] = mfma1k(pf0.s, vhi(W1), of[u][3]);                         \
        of[u][3] = mfma1k(pf1.s, vhi(W3), of[u][3]);                         \
    } } while (0)

__global__ __launch_bounds__(256, 2) void attn_kernel(
    const __hip_bfloat16* __restrict__ qbf,
    const __hip_bfloat16* __restrict__ kbf,
    const __hip_bfloat16* __restrict__ vbf,
    float* __restrict__ Opart, float* __restrict__ lpart,
    float* __restrict__ outz)
{
    __shared__ __align__(16) char pool[16384];
    char* bufA = pool;
    char* bufB = pool + 8192;

    const int tid = threadIdx.x;
    if (blockIdx.x == 0) {
        #pragma unroll
        for (int z = 0; z < 4; ++z)
            ((float4*)outz)[tid * 4 + z] = (float4){0.f, 0.f, 0.f, 0.f};
    }

    const int w    = tid >> 6;
    const int lane = tid & 63;
    const int l16  = lane & 15;
    const int quad = lane >> 4;
    const int qb   = blockIdx.x >> 4;
    const int bg   = blockIdx.x & 15;
    const int r0   = qb * 256 + w * 64;               // 64 q-rows per wave
    const int fo32 = l16 * 16 + (quad & 1) * 8;
    const int qh   = quad >> 1;
    const int lb   = lane * 16;
    const int stb  = tid * 16;

    bf16x8 qf32[4][2];
    #pragma unroll
    for (int u = 0; u < 4; ++u)
        #pragma unroll
        for (int p = 0; p < 2; ++p)
            qf32[u][p] = *(const bf16x8*)(qbf +
                ((((r0 >> 4) + u) * 4 + p * 2 + qh) << 8) + fo32);

    f32x4 of[4][4];
    float lp[4] = {0.f, 0.f, 0.f, 0.f};
    #pragma unroll
    for (int u = 0; u < 4; ++u)
        #pragma unroll
        for (int n = 0; n < 4; ++n)
            of[u][n] = (f32x4){0.f, 0.f, 0.f, 0.f};

    const char* gk = (const char*)kbf + (size_t)(bg * 16) * 4096 + stb;
    const char* gv = (const char*)vbf + (size_t)(bg * 16) * 4096 + stb;

    float4 ka, va, kb_, vb_;
    STAGE_L(ka, va);
    STAGE_W(bufA, ka, va);
    STAGE_L(kb_, vb_);
    __syncthreads();

    #pragma unroll 1
    for (int body = 0; body < 7; ++body) {
        STAGE_W(bufB, kb_, vb_);
        STAGE_L(ka, va);
        COMPUTE(bufA);
        __syncthreads();
        STAGE_W(bufA, ka, va);
        STAGE_L(kb_, vb_);
        COMPUTE(bufB);
        __syncthreads();
    }
    STAGE_W(bufB, kb_, vb_);
    COMPUTE(bufA);
    __syncthreads();
    COMPUTE(bufB);

    #pragma unroll
    for (int u = 0; u < 4; ++u) {
        float v = lp[u];
        v += __shfl_xor(v, 16, 64);
        v += __shfl_xor(v, 32, 64);
        lp[u] = v;
    }

    // row-major-partials store: Opart[row][bg][64], lpart[row][bg]
    #pragma unroll
    for (int u = 0; u < 4; ++u)
        #pragma unroll
        for (int n = 0; n < 4; ++n)
            #pragma unroll
            for (int r = 0; r < 4; ++r)
                Opart[((size_t)(r0 + u * 16 + quad * 4 + r) * 16 + bg) * 64
                      + n * 16 + l16] = of[u][n][r];
    if (quad == 0) {
        #pragma unroll
        for (int u = 0; u < 4; ++u)
            lpart[(r0 + u * 16 + l16) * 16 + bg] = lp[u];
    }
}

// ---------------------------------------------------------------------------
// Kernel 3: FUSED combine + sim. grid = 128 blocks x 512 thr; block a owns
// contraction k-range [a*64, a*64+64) (k = a*64+d), which needs exactly the
// 64 rows {(b,a) : b<64} -- a partitions rows, no duplication, no grid sync.
// Phase 1: sum 16 partials/row (one contiguous 4KB stream per row), /lsum,
// l2-normalize, bf16 -> LDS qn[64][68] (68-pad -> <=2-way banks, free).
// Phase 2: 8 waves = mi(4) x ks(2): per wave one 16-row Vn frag x 4 Qn
// frags x K=32 -> 4 mfma16; atomicAdd into out (zeroed by attn block 0).
// Replaces combine(2048 blk, 32MB read + 1MB qnb write) + sim(64 blk,
// latency-bound tail) + 1 dispatch boundary.
__global__ __launch_bounds__(512) void finish_kernel(
    const float* __restrict__ Opart, const float* __restrict__ lpart,
    const __hip_bfloat16* __restrict__ vnb,
    float* __restrict__ out)
{
    __shared__ __hip_bfloat16 qn[64][68];

    const int a   = blockIdx.x;                       // 0..127
    const int tid = threadIdx.x;                      // 0..511

    // ---- phase 1: 8 threads per row (8 cols each) ----
    {
        const int b  = tid >> 3;                      // 0..63
        const int c8 = tid & 7;
        const int r  = b * 128 + a;
        float acc[8] = {0.f, 0.f, 0.f, 0.f, 0.f, 0.f, 0.f, 0.f};
        #pragma unroll
        for (int g = 0; g < 16; ++g) {
            const float* src = Opart + ((size_t)r * 16 + g) * 64 + c8 * 8;
            float4 t0 = *(const float4*)(src);
            float4 t1 = *(const float4*)(src + 4);
            acc[0] += t0.x; acc[1] += t0.y; acc[2] += t0.z; acc[3] += t0.w;
            acc[4] += t1.x; acc[5] += t1.y; acc[6] += t1.z; acc[7] += t1.w;
        }
        float lsum = lpart[r * 16 + c8 * 2] + lpart[r * 16 + c8 * 2 + 1];
        lsum += __shfl_xor(lsum, 1, 64);
        lsum += __shfl_xor(lsum, 2, 64);
        lsum += __shfl_xor(lsum, 4, 64);
        const float inv_l = 1.0f / lsum;
        float ss = 0.f;
        #pragma unroll
        for (int c = 0; c < 8; ++c) {
            acc[c] *= inv_l;
            ss += acc[c] * acc[c];
        }
        ss += __shfl_xor(ss, 1, 64);
        ss += __shfl_xor(ss, 2, 64);
        ss += __shfl_xor(ss, 4, 64);
        const float inv = rsqrtf(fmaxf(ss, 1e-24f));
        bf16x8 pk;
        #pragma unroll
        for (int c = 0; c < 8; ++c)
            pk[c] = (__bf16)(acc[c] * inv);
        *(bf16x8*)&qn[b][c8 * 8] = pk;
    }
    __syncthreads();

    // ---- phase 2: GEMM, 8 waves = mi(4) x ks(2) ----
    {
        const int w    = tid >> 6;
        const int lane = tid & 63;
        const int l16  = lane & 15;
        const int quad = lane >> 4;
        const int ks   = w & 1;
        const int mi   = w >> 1;
        const int dq   = ks * 32 + quad * 8;

        bf16x8 af = *(const bf16x8*)(vnb +
            (size_t)(mi * 16 + l16) * 8192 + a * 64 + dq);
        f32x4 accd[4];
        #pragma unroll
        for (int ni = 0; ni < 4; ++ni) {
            bf16x8 bfv = *(const bf16x8*)&qn[ni * 16 + l16][dq];
            accd[ni] = mfma16(af, bfv, (f32x4){0.f, 0.f, 0.f, 0.f});
        }
        #pragma unroll
        for (int ni = 0; ni < 4; ++ni)
            #pragma unroll
            for (int r = 0; r < 4; ++r)
                atomicAdd(&out[(mi * 16 + quad * 4 + r) * 64 + ni * 16 + l16],
                          accd[ni][r] * (1.f / 128.f));
    }
}

// ---------------------------------------------------------------------------
extern "C" void kernel_launch(void* const* d_in, const int* in_sizes, int n_in,
                              void* d_out, int out_size, void* d_ws, size_t ws_size,
                              hipStream_t stream)
{
    const float* feat = (const float*)d_in[0];
    const float* Wq   = (const float*)d_in[1];
    const float* bq   = (const float*)d_in[2];
    const float* Wk   = (const float*)d_in[3];
    const float* bk   = (const float*)d_in[4];
    const float* Wv   = (const float*)d_in[5];
    const float* bv   = (const float*)d_in[6];
    float* out = (float*)d_out;

    const size_t MB = 1u << 20;
    char* ws = (char*)d_ws;
    __hip_bfloat16* qbf = (__hip_bfloat16*)(ws);              // 1 MB (frag-tiled, pre-scaled)
    __hip_bfloat16* kbf = (__hip_bfloat16*)(ws + 1 * MB);     // 1 MB (fragment-linear)
    __hip_bfloat16* vbf = (__hip_bfloat16*)(ws + 2 * MB);     // 1 MB (fragment-linear)
    __hip_bfloat16* vnb = (__hip_bfloat16*)(ws + 3 * MB);     // 1 MB (row-major)
    float* Opart = (float*)(ws + 4 * MB);                     // 32 MB (8192 x 16 x 64)
    float* lpart = (float*)(ws + 36 * MB);                    // 512 KB (8192 x 16)

    proj_kernel<<<256, 256, 0, stream>>>(feat, Wq, bq, Wk, bk, Wv, bv,
                                         qbf, kbf, vbf, vnb);
    attn_kernel<<<512, 256, 0, stream>>>(qbf, kbf, vbf, Opart, lpart, out);
    finish_kernel<<<128, 512, 0, stream>>>(Opart, lpart, vnb, out);
}